// Round 10
// baseline (55.627 us; speedup 1.0000x reference)
//
#include <hip/hip_runtime.h>
#include <math.h>

#define BB 8192
#define DD 4096
#define EE 64

constexpr float NOISE_EPS = 0.01f;
constexpr int BM = 64;              // rows per block (main GEMM)

typedef __attribute__((ext_vector_type(8))) _Float16 f16x8;
typedef __attribute__((ext_vector_type(2))) _Float16 f16x2;
typedef __attribute__((ext_vector_type(4))) float    f32x4;

__device__ __forceinline__ void split8(const float4& a, const float4& b,
                                       f16x8& hi, f16x8& mi) {
    float v[8] = {a.x, a.y, a.z, a.w, b.x, b.y, b.z, b.w};
    #pragma unroll
    for (int j = 0; j < 8; ++j) {
        _Float16 h = (_Float16)v[j];          // RN
        hi[j] = h;
        mi[j] = (_Float16)(v[j] - (float)h);
    }
}

__device__ __forceinline__ void gl_lds16(const void* g, void* l) {
    __builtin_amdgcn_global_load_lds(
        (const __attribute__((address_space(1))) unsigned*)g,
        (__attribute__((address_space(3))) unsigned*)l, 16, 0, 0);
}

// ---- pre-pass: pack weights into fp16 hi/mid planes in FRAGMENT order ----
// wpk chunk T (16 KB, T = global 32-k chunk): [cb 0..7][plane 0..1][lane 0..63] x 16B
// content(cb,p,lane): 8 fp16, weight row cb*16+(lane&15), k = T*32+(lane>>4)*8..
__global__ __launch_bounds__(256) void wsplit_pack(
    const float* __restrict__ gw, const float* __restrict__ ngw,
    char* __restrict__ wpk)
{
    const int gid = blockIdx.x * 256 + threadIdx.x;   // 65536 threads
    const int r   = gid >> 9;                         // 0..127
    const int kc  = gid & 511;                        // 8-float chunk in row
    const int k0  = kc * 8;
    const float* src = (r < EE) ? gw + (size_t)r * DD + k0
                                : ngw + (size_t)(r - EE) * DD + k0;
    float4 a = *reinterpret_cast<const float4*>(src);
    float4 b = *reinterpret_cast<const float4*>(src + 4);
    f16x8 hi, mi;
    split8(a, b, hi, mi);
    const int T    = k0 >> 5;
    const int kq   = (k0 >> 3) & 3;
    const int cb   = r >> 4;
    const int lane = kq * 16 + (r & 15);
    char* base = wpk + (size_t)T * 16384;
    *reinterpret_cast<f16x8*>(base + ((cb * 2 + 0) * 64 + lane) * 16) = hi;
    *reinterpret_cast<f16x8*>(base + ((cb * 2 + 1) * 64 + lane) * 16) = mi;
}

// ------------------------------- main GEMM --------------------------------
// K-step = 128 (4 chunks of 32): ONE barrier + ONE counted vmcnt per step.
// x double-buffered 32KB LDS tiles via global_load_lds (issue AFTER barrier);
// B direct global->reg, JIT-reloaded 2 chunks ahead into the consumed set.
template <int SK>
__global__ __launch_bounds__(512, 4) void gating_main(
    const float* __restrict__ x,
    const char*  __restrict__ wpk,
    float* __restrict__ partial)       // [SK][BB][128]
{
    constexpr int KC   = DD / SK;
    constexpr int NKS  = KC / 128;      // K-steps (>= 8 for SK<=4)
    constexpr int GMAX = 4 * NKS - 1;   // last 32-k chunk index in this sk part

    __shared__ __align__(1024) char xls_[2][32768];  // [buf][chunk 0..3][64 rows][128 B]

    const int tid  = threadIdx.x;
    const int bid  = blockIdx.x;
    const int sk   = bid & (SK - 1);
    const int row0 = (bid / SK) * BM;
    const int lane = tid & 63;
    const int wv   = tid >> 6;          // 8 waves: 2M x 4N
    const int m2   = wv & 1;            // row half: m2*32
    const int n2   = wv >> 1;           // col group: n2*32
    const int l15  = lane & 15;
    const int kq   = lane >> 4;

    // x staging: thread (r = tid>>3, slot s = tid&7); source k pre-swizzled
    const int r_ = tid >> 3, s_ = tid & 7;
    const float* xg = x + (size_t)(row0 + r_) * DD + sk * KC
                        + ((s_ ^ (r_ & 7)) << 2);

    // A-frag LDS byte offsets (chunk adds c*8192)
    int aoff[2][2];
    #pragma unroll
    for (int mb = 0; mb < 2; ++mb) {
        const int ar = m2 * 32 + mb * 16 + l15;
        #pragma unroll
        for (int u = 0; u < 2; ++u)
            aoff[mb][u] = ar * 128 + (((kq * 2 + u) ^ (ar & 7)) << 4);
    }

    // B direct-from-global: per-lane base + per-(cb,plane) offsets
    const char* wpkB = wpk + ((size_t)(sk * NKS * 4) << 14) + lane * 16;
    const int oh0 = ((n2 * 2 + 0) * 2 + 0) * 1024;
    const int om0 = ((n2 * 2 + 0) * 2 + 1) * 1024;
    const int oh1 = ((n2 * 2 + 1) * 2 + 0) * 1024;
    const int om1 = ((n2 * 2 + 1) * 2 + 1) * 1024;

    f32x4 acc00 = {0.f,0.f,0.f,0.f}, acc01 = {0.f,0.f,0.f,0.f};
    f32x4 acc10 = {0.f,0.f,0.f,0.f}, acc11 = {0.f,0.f,0.f,0.f};

    #define LOADB(g, H0, M0, H1, M1) do {                                      \
        const char* _b = wpkB + ((size_t)(g) << 14);                           \
        H0 = *reinterpret_cast<const f16x8*>(_b + oh0);                        \
        M0 = *reinterpret_cast<const f16x8*>(_b + om0);                        \
        H1 = *reinterpret_cast<const f16x8*>(_b + oh1);                        \
        M1 = *reinterpret_cast<const f16x8*>(_b + om1);                        \
    } while (0)

    #define CHUNK(c, H0, M0, H1, M1) do {                                      \
        const char* _xb = bufc + (c) * 8192;                                   \
        float4 a00 = *reinterpret_cast<const float4*>(_xb + aoff[0][0]);       \
        float4 a01 = *reinterpret_cast<const float4*>(_xb + aoff[0][1]);       \
        float4 a10 = *reinterpret_cast<const float4*>(_xb + aoff[1][0]);       \
        float4 a11 = *reinterpret_cast<const float4*>(_xb + aoff[1][1]);       \
        f16x8 ah0, am0, ah1, am1;                                              \
        split8(a00, a01, ah0, am0);                                            \
        split8(a10, a11, ah1, am1);                                            \
        acc00 = __builtin_amdgcn_mfma_f32_16x16x32_f16(ah0, H0, acc00, 0,0,0); \
        acc01 = __builtin_amdgcn_mfma_f32_16x16x32_f16(ah0, H1, acc01, 0,0,0); \
        acc10 = __builtin_amdgcn_mfma_f32_16x16x32_f16(ah1, H0, acc10, 0,0,0); \
        acc11 = __builtin_amdgcn_mfma_f32_16x16x32_f16(ah1, H1, acc11, 0,0,0); \
        acc00 = __builtin_amdgcn_mfma_f32_16x16x32_f16(am0, H0, acc00, 0,0,0); \
        acc01 = __builtin_amdgcn_mfma_f32_16x16x32_f16(am0, H1, acc01, 0,0,0); \
        acc10 = __builtin_amdgcn_mfma_f32_16x16x32_f16(am1, H0, acc10, 0,0,0); \
        acc11 = __builtin_amdgcn_mfma_f32_16x16x32_f16(am1, H1, acc11, 0,0,0); \
        acc00 = __builtin_amdgcn_mfma_f32_16x16x32_f16(ah0, M0, acc00, 0,0,0); \
        acc01 = __builtin_amdgcn_mfma_f32_16x16x32_f16(ah0, M1, acc01, 0,0,0); \
        acc10 = __builtin_amdgcn_mfma_f32_16x16x32_f16(ah1, M0, acc10, 0,0,0); \
        acc11 = __builtin_amdgcn_mfma_f32_16x16x32_f16(ah1, M1, acc11, 0,0,0); \
        { const int _g = 4 * t + (c) + 2;                                      \
          LOADB((_g <= GMAX) ? _g : GMAX, H0, M0, H1, M1); }                   \
    } while (0)

    f16x8 p0, p1, p2, p3;   // B set for even chunks
    f16x8 q0, q1, q2, q3;   // B set for odd chunks

    // ---- prologue: stage x(0); preload B chunks 0,1 ----
    {
        char* d = xls_[0] + wv * 1024;
        gl_lds16(xg,      d);
        gl_lds16(xg + 32, d + 8192);
        gl_lds16(xg + 64, d + 16384);
        gl_lds16(xg + 96, d + 24576);
    }
    LOADB(0, p0, p1, p2, p3);
    LOADB(1, q0, q1, q2, q3);

    for (int t = 0; t < NKS; ++t) {
        // entering: outstanding (oldest first) = x(t) x4, B(4t) x4, B(4t+1) x4
        asm volatile("s_waitcnt vmcnt(8)" ::: "memory");   // x(t) LDS writes done
        __builtin_amdgcn_s_barrier();                      // block-wide visible

        // issue x(t+1) into the freed buffer (after barrier -> no WAR race)
        {
            const int tn = (t + 1 < NKS) ? t + 1 : t;      // clamped tail
            const float* s = xg + (size_t)tn * 128;
            char* d = xls_[(t + 1) & 1] + wv * 1024;
            gl_lds16(s,      d);
            gl_lds16(s + 32, d + 8192);
            gl_lds16(s + 64, d + 16384);
            gl_lds16(s + 96, d + 24576);
        }

        const char* bufc = xls_[t & 1];
        CHUNK(0, p0, p1, p2, p3);
        CHUNK(1, q0, q1, q2, q3);
        CHUNK(2, p0, p1, p2, p3);
        CHUNK(3, q0, q1, q2, q3);
    }
    asm volatile("s_waitcnt vmcnt(0)" ::: "memory");       // drain clamped tail

    #undef LOADB
    #undef CHUNK

    // ---- partial logits out (deterministic, no atomics) ----
    const size_t pbase = ((size_t)sk * BB + row0) * 128;
    #pragma unroll
    for (int j = 0; j < 4; ++j) {
        const int r0 = m2 * 32 + kq * 4 + j;
        const int c0 = n2 * 32 + l15;
        partial[pbase + (size_t)r0 * 128 + c0]             = acc00[j];
        partial[pbase + (size_t)r0 * 128 + c0 + 16]        = acc01[j];
        partial[pbase + (size_t)(r0 + 16) * 128 + c0]      = acc10[j];
        partial[pbase + (size_t)(r0 + 16) * 128 + c0 + 16] = acc11[j];
    }
}

// ------------------------------- epilogue ---------------------------------
template <int SK>
__global__ __launch_bounds__(512) void gating_epi(
    const float* __restrict__ partial,   // [SK][BB][128]
    const float* __restrict__ noise,     // [B, E]
    float* __restrict__ out)             // gates [B,E] then load [B,E]
{
    const int tid  = threadIdx.x;
    const int wv   = tid >> 6;
    const int lane = tid & 63;
    const int l15  = lane & 15;
    const int kq   = lane >> 4;
    const int grow = blockIdx.x * 32 + wv * 4 + kq;
    const int s    = l15;                // experts 4s..4s+3

    const float* pb = partial + (size_t)grow * 128 + 4 * s;
    float4 c4 = {0.f,0.f,0.f,0.f}, n4 = {0.f,0.f,0.f,0.f};
    #pragma unroll
    for (int k = 0; k < SK; ++k) {
        const float* p = pb + (size_t)k * BB * 128;
        float4 a = *reinterpret_cast<const float4*>(p);
        float4 b = *reinterpret_cast<const float4*>(p + 64);
        c4.x += a.x; c4.y += a.y; c4.z += a.z; c4.w += a.w;
        n4.x += b.x; n4.y += b.y; n4.z += b.z; n4.w += b.w;
    }

    float4 nz = *reinterpret_cast<const float4*>(noise + (size_t)grow * EE + 4 * s);

    float cc[4] = {c4.x, c4.y, c4.z, c4.w};
    float nl[4] = {n4.x, n4.y, n4.z, n4.w};
    float m1 = -3.4e38f, m2 = -3.4e38f;
    int   i1 = -1, i2 = -1;
    float cmax = -3.4e38f;
    #pragma unroll
    for (int j = 0; j < 4; ++j) {
        const int e = 4 * s + j;
        float sp  = fmaxf(nl[j], 0.0f) + log1pf(expf(-fabsf(nl[j])));  // softplus
        float nzj = (j == 0) ? nz.x : (j == 1) ? nz.y : (j == 2) ? nz.z : nz.w;
        float vno = fmaf(nzj * sp, NOISE_EPS, cc[j]);
        if (vno > m1)      { m2 = m1; i2 = i1; m1 = vno; i1 = e; }
        else if (vno > m2) { m2 = vno; i2 = e; }
        cmax = fmaxf(cmax, cc[j]);
    }

    // 16-lane reduce: top-2 with (value, lower-index) tiebreak + clean max
    #pragma unroll
    for (int m = 1; m < 16; m <<= 1) {
        float b1 = __shfl_xor(m1, m, 16);
        int  bi1 = __shfl_xor(i1, m, 16);
        float b2 = __shfl_xor(m2, m, 16);
        int  bi2 = __shfl_xor(i2, m, 16);
        cmax = fmaxf(cmax, __shfl_xor(cmax, m, 16));

        bool bwin = (b1 > m1) || (b1 == m1 && bi1 < i1);
        float t1; int ti1; float t2; int ti2;
        if (bwin) {
            t1 = b1; ti1 = bi1;
            bool aw = (m1 > b2) || (m1 == b2 && i1 < bi2);
            t2 = aw ? m1 : b2; ti2 = aw ? i1 : bi2;
        } else {
            t1 = m1; ti1 = i1;
            bool bw = (b1 > m2) || (b1 == m2 && bi1 < i2);
            t2 = bw ? b1 : m2; ti2 = bw ? bi1 : i2;
        }
        m1 = t1; i1 = ti1; m2 = t2; i2 = ti2;
    }

    float tq = expf(m2 - m1);
    float p1 = 1.0f / (1.0f + tq);
    float p2 = tq * p1;

    float e0 = expf(cc[0] - cmax);
    float e1 = expf(cc[1] - cmax);
    float e2 = expf(cc[2] - cmax);
    float e3 = expf(cc[3] - cmax);
    float sum = e0 + e1 + e2 + e3;
    #pragma unroll
    for (int m = 1; m < 16; m <<= 1) sum += __shfl_xor(sum, m, 16);
    float inv = 1.0f / sum;

    const int eb = 4 * s;
    float4 gt;
    gt.x = (eb     == i1) ? p1 : (eb     == i2) ? p2 : 0.0f;
    gt.y = (eb + 1 == i1) ? p1 : (eb + 1 == i2) ? p2 : 0.0f;
    gt.z = (eb + 2 == i1) ? p1 : (eb + 2 == i2) ? p2 : 0.0f;
    gt.w = (eb + 3 == i1) ? p1 : (eb + 3 == i2) ? p2 : 0.0f;
    float4 ld = {e0 * inv, e1 * inv, e2 * inv, e3 * inv};

    *reinterpret_cast<float4*>(out + (size_t)grow * EE + eb) = gt;
    *reinterpret_cast<float4*>(out + (size_t)BB * EE + (size_t)grow * EE + eb) = ld;
}

extern "C" void kernel_launch(void* const* d_in, const int* in_sizes, int n_in,
                              void* d_out, int out_size, void* d_ws, size_t ws_size,
                              hipStream_t stream) {
    const float* x     = (const float*)d_in[0];
    const float* gw    = (const float*)d_in[1];
    const float* ngw   = (const float*)d_in[2];
    const float* noise = (const float*)d_in[3];
    float* out = (float*)d_out;

    char*  wpk     = (char*)d_ws;                                // 2 MB packed w
    float* partial = (float*)(wpk + (size_t)2 * 1024 * 1024);    // SK * 4 MB

    const size_t MB = 1024 * 1024;

    hipLaunchKernelGGL(wsplit_pack, dim3(256), dim3(256), 0, stream, gw, ngw, wpk);

    if (ws_size >= 18 * MB) {
        hipLaunchKernelGGL(gating_main<4>, dim3((BB / BM) * 4), dim3(512), 0, stream,
                           x, wpk, partial);
        hipLaunchKernelGGL(gating_epi<4>, dim3(BB / 32), dim3(512), 0, stream,
                           partial, noise, out);
    } else if (ws_size >= 10 * MB) {
        hipLaunchKernelGGL(gating_main<2>, dim3((BB / BM) * 2), dim3(512), 0, stream,
                           x, wpk, partial);
        hipLaunchKernelGGL(gating_epi<2>, dim3(BB / 32), dim3(512), 0, stream,
                           partial, noise, out);
    } else {
        hipLaunchKernelGGL(gating_main<1>, dim3(BB / BM), dim3(512), 0, stream,
                           x, wpk, partial);
        hipLaunchKernelGGL(gating_epi<1>, dim3(BB / 32), dim3(512), 0, stream,
                           partial, noise, out);
    }
}

// Round 11
// 49.695 us; speedup vs baseline: 1.1194x; 1.1194x over previous
//
#include <hip/hip_runtime.h>
#include <math.h>

#define BB 8192
#define DD 4096
#define EE 64

constexpr float NOISE_EPS = 0.01f;
constexpr int BM = 64;              // rows per block (main GEMM)

typedef __attribute__((ext_vector_type(8))) _Float16 f16x8;
typedef __attribute__((ext_vector_type(4))) float    f32x4;

__device__ __forceinline__ void split8(const float4& a, const float4& b,
                                       f16x8& hi, f16x8& mi) {
    float v[8] = {a.x, a.y, a.z, a.w, b.x, b.y, b.z, b.w};
    #pragma unroll
    for (int j = 0; j < 8; ++j) {
        _Float16 h = (_Float16)v[j];          // RN
        hi[j] = h;
        mi[j] = (_Float16)(v[j] - (float)h);
    }
}

// ---- pre-pass: pack weights into fp16 hi/mid planes in FRAGMENT order ----
// wpk chunk T (16 KB, T = global 32-k chunk): [cb 0..7][plane 0..1][lane 0..63] x 16B
// content(cb,p,lane): 8 fp16, weight row cb*16+(lane&15), k = T*32+(lane>>4)*8..
__global__ __launch_bounds__(256) void wsplit_pack(
    const float* __restrict__ gw, const float* __restrict__ ngw,
    char* __restrict__ wpk)
{
    const int gid = blockIdx.x * 256 + threadIdx.x;   // 65536 threads
    const int r   = gid >> 9;                         // 0..127
    const int kc  = gid & 511;                        // 8-float chunk in row
    const int k0  = kc * 8;
    const float* src = (r < EE) ? gw + (size_t)r * DD + k0
                                : ngw + (size_t)(r - EE) * DD + k0;
    float4 a = *reinterpret_cast<const float4*>(src);
    float4 b = *reinterpret_cast<const float4*>(src + 4);
    f16x8 hi, mi;
    split8(a, b, hi, mi);
    const int T    = k0 >> 5;
    const int kq   = (k0 >> 3) & 3;
    const int cb   = r >> 4;
    const int lane = kq * 16 + (r & 15);
    char* base = wpk + (size_t)T * 16384;
    *reinterpret_cast<f16x8*>(base + ((cb * 2 + 0) * 64 + lane) * 16) = hi;
    *reinterpret_cast<f16x8*>(base + ((cb * 2 + 1) * 64 + lane) * 16) = mi;
}

// ------------------------------- main GEMM --------------------------------
// 8 waves = 1M x 8N: wave owns 64 rows x 16 cols -> each B chunk read exactly
// once per block (minimal L2/TCP stream). x is reg-staged (T14): global->reg,
// split ONCE to fp16 hi/mid, ds_write to swizzled 2-plane tile; per-chunk work
// is pure ds_read_b128 + MFMA. K-step=64, double-buffered; one lgkmcnt+barrier
// per step; ALL global loads compiler-counted (stay in flight across barriers).
template <int SK>
__global__ __launch_bounds__(512, 4) void gating_main(
    const float* __restrict__ x,
    const char*  __restrict__ wpk,
    float* __restrict__ partial)       // [SK][BB][128]
{
    constexpr int KC   = DD / SK;
    constexpr int NKS  = KC / 64;       // K-steps (16 for SK=4), even
    constexpr int GMAX = 2 * NKS - 1;   // last 32-k chunk index in this part

    // [buf][row 0..63][plane 0..1][64k as 8 swizzled 16B slots] = 2 x 16 KB
    __shared__ __align__(1024) char xls[2][16384];

    const int tid  = threadIdx.x;
    const int bid  = blockIdx.x;
    const int sk   = bid & (SK - 1);
    const int row0 = (bid / SK) * BM;
    const int lane = tid & 63;
    const int n8   = tid >> 6;          // wave = col group n8*16
    const int l15  = lane & 15;
    const int kq   = lane >> 4;

    // ---- x staging (reg-staged): thread sr=tid>>3 row, sj=tid&7 8-k slot ----
    const int sr = tid >> 3;            // 0..63
    const int sj = tid & 7;             // 0..7
    const float* xg = x + (size_t)(row0 + sr) * DD + sk * KC + sj * 8;
    // LDS write offsets (plane p), slot swizzled by row
    const int wo0 = sr * 256 + 0 * 128 + ((sj ^ (sr & 7)) << 4);
    const int wo1 = sr * 256 + 1 * 128 + ((sj ^ (sr & 7)) << 4);

    // ---- A-frag read offsets: ms=0..3 (rows ms*16+l15), plane p, chunk c ----
    int rbase[4], swz[4];
    #pragma unroll
    for (int ms = 0; ms < 4; ++ms) {
        const int r = ms * 16 + l15;
        rbase[ms] = r * 256;
        swz[ms]   = r & 7;
    }

    // ---- B direct-from-global (frag-packed, L2): 1 cb per wave ----
    const char* wpkB = wpk + ((size_t)(sk * NKS * 2) << 14) + lane * 16;
    const int oh = (2 * n8 + 0) * 1024;
    const int om = (2 * n8 + 1) * 1024;

    f32x4 acc0 = {0.f,0.f,0.f,0.f}, acc1 = {0.f,0.f,0.f,0.f};
    f32x4 acc2 = {0.f,0.f,0.f,0.f}, acc3 = {0.f,0.f,0.f,0.f};

    #define LOADB(g, H, M) do {                                                \
        const char* _b = wpkB + ((size_t)(g) << 14);                           \
        H = *reinterpret_cast<const f16x8*>(_b + oh);                          \
        M = *reinterpret_cast<const f16x8*>(_b + om);                          \
    } while (0)

    // one 32-k chunk: 8 ds_read_b128 + 12 MFMA + JIT B reload (2 ahead)
    #define CHUNK(bufp, gc, H, M) do {                                         \
        const char* _xb = (bufp);                                              \
        const int _c = (gc) & 1;                                               \
        f16x8 ah0 = *reinterpret_cast<const f16x8*>(_xb + rbase[0] +           \
                        ((((_c << 2) | kq) ^ swz[0]) << 4));                   \
        f16x8 am0 = *reinterpret_cast<const f16x8*>(_xb + rbase[0] + 128 +     \
                        ((((_c << 2) | kq) ^ swz[0]) << 4));                   \
        f16x8 ah1 = *reinterpret_cast<const f16x8*>(_xb + rbase[1] +           \
                        ((((_c << 2) | kq) ^ swz[1]) << 4));                   \
        f16x8 am1 = *reinterpret_cast<const f16x8*>(_xb + rbase[1] + 128 +     \
                        ((((_c << 2) | kq) ^ swz[1]) << 4));                   \
        f16x8 ah2 = *reinterpret_cast<const f16x8*>(_xb + rbase[2] +           \
                        ((((_c << 2) | kq) ^ swz[2]) << 4));                   \
        f16x8 am2 = *reinterpret_cast<const f16x8*>(_xb + rbase[2] + 128 +     \
                        ((((_c << 2) | kq) ^ swz[2]) << 4));                   \
        f16x8 ah3 = *reinterpret_cast<const f16x8*>(_xb + rbase[3] +           \
                        ((((_c << 2) | kq) ^ swz[3]) << 4));                   \
        f16x8 am3 = *reinterpret_cast<const f16x8*>(_xb + rbase[3] + 128 +     \
                        ((((_c << 2) | kq) ^ swz[3]) << 4));                   \
        acc0 = __builtin_amdgcn_mfma_f32_16x16x32_f16(ah0, H, acc0, 0,0,0);    \
        acc1 = __builtin_amdgcn_mfma_f32_16x16x32_f16(ah1, H, acc1, 0,0,0);    \
        acc2 = __builtin_amdgcn_mfma_f32_16x16x32_f16(ah2, H, acc2, 0,0,0);    \
        acc3 = __builtin_amdgcn_mfma_f32_16x16x32_f16(ah3, H, acc3, 0,0,0);    \
        acc0 = __builtin_amdgcn_mfma_f32_16x16x32_f16(am0, H, acc0, 0,0,0);    \
        acc1 = __builtin_amdgcn_mfma_f32_16x16x32_f16(am1, H, acc1, 0,0,0);    \
        acc2 = __builtin_amdgcn_mfma_f32_16x16x32_f16(am2, H, acc2, 0,0,0);    \
        acc3 = __builtin_amdgcn_mfma_f32_16x16x32_f16(am3, H, acc3, 0,0,0);    \
        acc0 = __builtin_amdgcn_mfma_f32_16x16x32_f16(ah0, M, acc0, 0,0,0);    \
        acc1 = __builtin_amdgcn_mfma_f32_16x16x32_f16(ah1, M, acc1, 0,0,0);    \
        acc2 = __builtin_amdgcn_mfma_f32_16x16x32_f16(ah2, M, acc2, 0,0,0);    \
        acc3 = __builtin_amdgcn_mfma_f32_16x16x32_f16(ah3, M, acc3, 0,0,0);    \
        { const int _g = (gc) + 2;                                             \
          LOADB((_g <= GMAX) ? _g : GMAX, H, M); }                             \
    } while (0)

    #define WSPLIT(bp, V0, V1) do {                                            \
        f16x8 _hi, _mi;                                                        \
        split8(V0, V1, _hi, _mi);                                              \
        *reinterpret_cast<f16x8*>((bp) + wo0) = _hi;                           \
        *reinterpret_cast<f16x8*>((bp) + wo1) = _mi;                           \
    } while (0)

    char* buf0 = (char*)xls[0];
    char* buf1 = (char*)xls[1];

    float4 xA0, xA1, xB0, xB1;
    f16x8 pH, pM, qH, qM;

    // ---- prologue: x(0)->buf0, x(1)->regs, B(0),B(1)->regs ----
    xA0 = *reinterpret_cast<const float4*>(xg);
    xA1 = *reinterpret_cast<const float4*>(xg + 4);
    xB0 = *reinterpret_cast<const float4*>(xg + 64);
    xB1 = *reinterpret_cast<const float4*>(xg + 64 + 4);
    WSPLIT(buf0, xA0, xA1);
    LOADB(0, pH, pM);
    LOADB(1, qH, qM);

    // ---- main loop (2 steps per trip; 1 lgkmcnt+barrier per step) ----
    for (int t = 0; t < NKS; t += 2) {
        // even step t: compute buf0 (chunks 2t,2t+1); write x(t+1); load x(t+2)
        asm volatile("s_waitcnt lgkmcnt(0)" ::: "memory");
        __builtin_amdgcn_s_barrier();
        if (t + 2 < NKS) {
            xA0 = *reinterpret_cast<const float4*>(xg + (size_t)(t + 2) * 64);
            xA1 = *reinterpret_cast<const float4*>(xg + (size_t)(t + 2) * 64 + 4);
        }
        WSPLIT(buf1, xB0, xB1);                 // x(t+1) -> other buffer
        CHUNK(buf0, 2 * t,     pH, pM);
        CHUNK(buf0, 2 * t + 1, qH, qM);

        // odd step t+1: compute buf1; write x(t+2); load x(t+3)
        asm volatile("s_waitcnt lgkmcnt(0)" ::: "memory");
        __builtin_amdgcn_s_barrier();
        if (t + 3 < NKS) {
            xB0 = *reinterpret_cast<const float4*>(xg + (size_t)(t + 3) * 64);
            xB1 = *reinterpret_cast<const float4*>(xg + (size_t)(t + 3) * 64 + 4);
        }
        if (t + 2 < NKS) WSPLIT(buf0, xA0, xA1); // x(t+2) -> buffer 0
        CHUNK(buf1, 2 * t + 2, pH, pM);
        CHUNK(buf1, 2 * t + 3, qH, qM);
    }

    #undef LOADB
    #undef CHUNK
    #undef WSPLIT

    // ---- partial logits out (deterministic, no atomics) ----
    const size_t pbase = ((size_t)sk * BB + row0) * 128;
    #pragma unroll
    for (int ms = 0; ms < 4; ++ms) {
        f32x4 a = (ms == 0) ? acc0 : (ms == 1) ? acc1 : (ms == 2) ? acc2 : acc3;
        #pragma unroll
        for (int j = 0; j < 4; ++j) {
            const int r = ms * 16 + kq * 4 + j;
            const int c = n8 * 16 + l15;
            partial[pbase + (size_t)r * 128 + c] = a[j];
        }
    }
}

// ------------------------------- epilogue ---------------------------------
template <int SK>
__global__ __launch_bounds__(512) void gating_epi(
    const float* __restrict__ partial,   // [SK][BB][128]
    const float* __restrict__ noise,     // [B, E]
    float* __restrict__ out)             // gates [B,E] then load [B,E]
{
    const int tid  = threadIdx.x;
    const int wv   = tid >> 6;
    const int lane = tid & 63;
    const int l15  = lane & 15;
    const int kq   = lane >> 4;
    const int grow = blockIdx.x * 32 + wv * 4 + kq;
    const int s    = l15;                // experts 4s..4s+3

    const float* pb = partial + (size_t)grow * 128 + 4 * s;
    float4 c4 = {0.f,0.f,0.f,0.f}, n4 = {0.f,0.f,0.f,0.f};
    #pragma unroll
    for (int k = 0; k < SK; ++k) {
        const float* p = pb + (size_t)k * BB * 128;
        float4 a = *reinterpret_cast<const float4*>(p);
        float4 b = *reinterpret_cast<const float4*>(p + 64);
        c4.x += a.x; c4.y += a.y; c4.z += a.z; c4.w += a.w;
        n4.x += b.x; n4.y += b.y; n4.z += b.z; n4.w += b.w;
    }

    float4 nz = *reinterpret_cast<const float4*>(noise + (size_t)grow * EE + 4 * s);

    float cc[4] = {c4.x, c4.y, c4.z, c4.w};
    float nl[4] = {n4.x, n4.y, n4.z, n4.w};
    float m1 = -3.4e38f, m2 = -3.4e38f;
    int   i1 = -1, i2 = -1;
    float cmax = -3.4e38f;
    #pragma unroll
    for (int j = 0; j < 4; ++j) {
        const int e = 4 * s + j;
        float sp  = fmaxf(nl[j], 0.0f) + log1pf(expf(-fabsf(nl[j])));  // softplus
        float nzj = (j == 0) ? nz.x : (j == 1) ? nz.y : (j == 2) ? nz.z : nz.w;
        float vno = fmaf(nzj * sp, NOISE_EPS, cc[j]);
        if (vno > m1)      { m2 = m1; i2 = i1; m1 = vno; i1 = e; }
        else if (vno > m2) { m2 = vno; i2 = e; }
        cmax = fmaxf(cmax, cc[j]);
    }

    // 16-lane reduce: top-2 with (value, lower-index) tiebreak + clean max
    #pragma unroll
    for (int m = 1; m < 16; m <<= 1) {
        float b1 = __shfl_xor(m1, m, 16);
        int  bi1 = __shfl_xor(i1, m, 16);
        float b2 = __shfl_xor(m2, m, 16);
        int  bi2 = __shfl_xor(i2, m, 16);
        cmax = fmaxf(cmax, __shfl_xor(cmax, m, 16));

        bool bwin = (b1 > m1) || (b1 == m1 && bi1 < i1);
        float t1; int ti1; float t2; int ti2;
        if (bwin) {
            t1 = b1; ti1 = bi1;
            bool aw = (m1 > b2) || (m1 == b2 && i1 < bi2);
            t2 = aw ? m1 : b2; ti2 = aw ? i1 : bi2;
        } else {
            t1 = m1; ti1 = i1;
            bool bw = (b1 > m2) || (b1 == m2 && bi1 < i2);
            t2 = bw ? b1 : m2; ti2 = bw ? bi1 : i2;
        }
        m1 = t1; i1 = ti1; m2 = t2; i2 = ti2;
    }

    float tq = expf(m2 - m1);
    float p1 = 1.0f / (1.0f + tq);
    float p2 = tq * p1;

    float e0 = expf(cc[0] - cmax);
    float e1 = expf(cc[1] - cmax);
    float e2 = expf(cc[2] - cmax);
    float e3 = expf(cc[3] - cmax);
    float sum = e0 + e1 + e2 + e3;
    #pragma unroll
    for (int m = 1; m < 16; m <<= 1) sum += __shfl_xor(sum, m, 16);
    float inv = 1.0f / sum;

    const int eb = 4 * s;
    float4 gt;
    gt.x = (eb     == i1) ? p1 : (eb     == i2) ? p2 : 0.0f;
    gt.y = (eb + 1 == i1) ? p1 : (eb + 1 == i2) ? p2 : 0.0f;
    gt.z = (eb + 2 == i1) ? p1 : (eb + 2 == i2) ? p2 : 0.0f;
    gt.w = (eb + 3 == i1) ? p1 : (eb + 3 == i2) ? p2 : 0.0f;
    float4 ld = {e0 * inv, e1 * inv, e2 * inv, e3 * inv};

    *reinterpret_cast<float4*>(out + (size_t)grow * EE + eb) = gt;
    *reinterpret_cast<float4*>(out + (size_t)BB * EE + (size_t)grow * EE + eb) = ld;
}

extern "C" void kernel_launch(void* const* d_in, const int* in_sizes, int n_in,
                              void* d_out, int out_size, void* d_ws, size_t ws_size,
                              hipStream_t stream) {
    const float* x     = (const float*)d_in[0];
    const float* gw    = (const float*)d_in[1];
    const float* ngw   = (const float*)d_in[2];
    const float* noise = (const float*)d_in[3];
    float* out = (float*)d_out;

    char*  wpk     = (char*)d_ws;                                // 2 MB packed w
    float* partial = (float*)(wpk + (size_t)2 * 1024 * 1024);    // SK * 4 MB

    const size_t MB = 1024 * 1024;

    hipLaunchKernelGGL(wsplit_pack, dim3(256), dim3(256), 0, stream, gw, ngw, wpk);

    if (ws_size >= 18 * MB) {
        hipLaunchKernelGGL(gating_main<4>, dim3((BB / BM) * 4), dim3(512), 0, stream,
                           x, wpk, partial);
        hipLaunchKernelGGL(gating_epi<4>, dim3(BB / 32), dim3(512), 0, stream,
                           partial, noise, out);
    } else if (ws_size >= 10 * MB) {
        hipLaunchKernelGGL(gating_main<2>, dim3((BB / BM) * 2), dim3(512), 0, stream,
                           x, wpk, partial);
        hipLaunchKernelGGL(gating_epi<2>, dim3(BB / 32), dim3(512), 0, stream,
                           partial, noise, out);
    } else {
        hipLaunchKernelGGL(gating_main<1>, dim3(BB / BM), dim3(512), 0, stream,
                           x, wpk, partial);
        hipLaunchKernelGGL(gating_epi<1>, dim3(BB / 32), dim3(512), 0, stream,
                           partial, noise, out);
    }
}

// Round 12
// 49.146 us; speedup vs baseline: 1.1319x; 1.0112x over previous
//
#include <hip/hip_runtime.h>
#include <math.h>

#define BB 8192
#define DD 4096
#define EE 64

constexpr float NOISE_EPS = 0.01f;
constexpr int BM = 64;              // rows per block (main GEMM)

typedef __attribute__((ext_vector_type(8))) _Float16 f16x8;
typedef __attribute__((ext_vector_type(4))) float    f32x4;

__device__ __forceinline__ void split8(const float4& a, const float4& b,
                                       f16x8& hi, f16x8& mi) {
    float v[8] = {a.x, a.y, a.z, a.w, b.x, b.y, b.z, b.w};
    #pragma unroll
    for (int j = 0; j < 8; ++j) {
        _Float16 h = (_Float16)v[j];          // RN
        hi[j] = h;
        mi[j] = (_Float16)(v[j] - (float)h);
    }
}

// ---- pre-pass: pack weights into fp16 hi/mid planes in FRAGMENT order ----
// wpk chunk T (16 KB, T = global 32-k chunk): [cb 0..7][plane 0..1][lane 0..63] x 16B
// content(cb,p,lane): 8 fp16, weight row cb*16+(lane&15), k = T*32+(lane>>4)*8..
__global__ __launch_bounds__(256) void wsplit_pack(
    const float* __restrict__ gw, const float* __restrict__ ngw,
    char* __restrict__ wpk)
{
    const int gid = blockIdx.x * 256 + threadIdx.x;   // 65536 threads
    const int r   = gid >> 9;                         // 0..127
    const int kc  = gid & 511;                        // 8-float chunk in row
    const int k0  = kc * 8;
    const float* src = (r < EE) ? gw + (size_t)r * DD + k0
                                : ngw + (size_t)(r - EE) * DD + k0;
    float4 a = *reinterpret_cast<const float4*>(src);
    float4 b = *reinterpret_cast<const float4*>(src + 4);
    f16x8 hi, mi;
    split8(a, b, hi, mi);
    const int T    = k0 >> 5;
    const int kq   = (k0 >> 3) & 3;
    const int cb   = r >> 4;
    const int lane = kq * 16 + (r & 15);
    char* base = wpk + (size_t)T * 16384;
    *reinterpret_cast<f16x8*>(base + ((cb * 2 + 0) * 64 + lane) * 16) = hi;
    *reinterpret_cast<f16x8*>(base + ((cb * 2 + 1) * 64 + lane) * 16) = mi;
}

// ------------------------------- main GEMM --------------------------------
// Producer/consumer wave split: waves 0..3 stage x (global->reg->split->LDS);
// waves 4..7 each own 2 column-blocks (32 cols) and run ds_read+MFMA with
// B fragments straight from the frag-packed global buffer (read-once/block).
// K-step = 64, double-buffered; 1 lgkmcnt+barrier per step; all global loads
// compiler-counted (stay in flight across barriers).
template <int SK>
__global__ __launch_bounds__(512, 4) void gating_main(
    const float* __restrict__ x,
    const char*  __restrict__ wpk,
    float* __restrict__ partial)       // [SK][BB][128]
{
    constexpr int KC   = DD / SK;
    constexpr int NKS  = KC / 64;       // K-steps (16 for SK=4), even
    constexpr int GMAX = 2 * NKS - 1;   // last 32-k chunk index in this part

    // [buf][row 0..63][plane 0..1][8 swizzled 16B k-slots] = 2 x 16 KB
    __shared__ __align__(1024) char xls[2][16384];

    const int tid  = threadIdx.x;
    const int bid  = blockIdx.x;
    const int sk   = bid & (SK - 1);
    const int row0 = (bid / SK) * BM;
    const int lane = tid & 63;
    const int wv   = tid >> 6;
    const bool producer = (wv < 4);
    const int l15  = lane & 15;
    const int kq   = lane >> 4;

    char* buf0 = (char*)xls[0];
    char* buf1 = (char*)xls[1];

    // =================== producer setup (waves 0..3) ===================
    const int pr = tid >> 2;            // 0..63 (valid for tid<256)
    const int ps = tid & 3;             // 16-float slot
    const float* xg = x + (size_t)(row0 + pr) * DD + sk * KC + ps * 16;
    const int swp   = pr & 7;
    const int wb    = pr * 256;
    const int wo_h0 = wb       + (((2 * ps)     ^ swp) << 4);
    const int wo_m0 = wb + 128 + (((2 * ps)     ^ swp) << 4);
    const int wo_h1 = wb       + (((2 * ps + 1) ^ swp) << 4);
    const int wo_m1 = wb + 128 + (((2 * ps + 1) ^ swp) << 4);

    #define LOADX(t, V0, V1, V2, V3) do {                                      \
        const float* _s = xg + (size_t)(t) * 64;                               \
        V0 = *reinterpret_cast<const float4*>(_s);                             \
        V1 = *reinterpret_cast<const float4*>(_s + 4);                         \
        V2 = *reinterpret_cast<const float4*>(_s + 8);                         \
        V3 = *reinterpret_cast<const float4*>(_s + 12);                        \
    } while (0)

    #define WSPLIT(bp, V0, V1, V2, V3) do {                                    \
        f16x8 _h, _m;                                                          \
        split8(V0, V1, _h, _m);                                                \
        *reinterpret_cast<f16x8*>((bp) + wo_h0) = _h;                          \
        *reinterpret_cast<f16x8*>((bp) + wo_m0) = _m;                          \
        split8(V2, V3, _h, _m);                                                \
        *reinterpret_cast<f16x8*>((bp) + wo_h1) = _h;                          \
        *reinterpret_cast<f16x8*>((bp) + wo_m1) = _m;                          \
    } while (0)

    // =================== consumer setup (waves 4..7) ===================
    const int cw = wv - 4;              // 0..3 ; owns cbs 2cw, 2cw+1
    int rbase[4], swz[4];
    #pragma unroll
    for (int ms = 0; ms < 4; ++ms) {
        const int r = ms * 16 + l15;
        rbase[ms] = r * 256;
        swz[ms]   = r & 7;
    }
    // consumer's 4 KB contiguous B slice: [cb0 hi][cb0 mi][cb1 hi][cb1 mi]
    const char* wpkB = wpk + ((size_t)(sk * NKS * 2) << 14)
                           + ((cw & 3) * 4096) + lane * 16;

    f32x4 acc[4][2];
    #pragma unroll
    for (int ms = 0; ms < 4; ++ms) {
        acc[ms][0] = {0.f, 0.f, 0.f, 0.f};
        acc[ms][1] = {0.f, 0.f, 0.f, 0.f};
    }

    #define LOADB(g, H0, M0, H1, M1) do {                                      \
        const char* _b = wpkB + ((size_t)(g) << 14);                           \
        H0 = *reinterpret_cast<const f16x8*>(_b);                              \
        M0 = *reinterpret_cast<const f16x8*>(_b + 1024);                       \
        H1 = *reinterpret_cast<const f16x8*>(_b + 2048);                       \
        M1 = *reinterpret_cast<const f16x8*>(_b + 3072);                       \
    } while (0)

    // one 32-k chunk: 8 ds_read_b128 + 24 MFMA + JIT B reload (2 ahead)
    #define CHUNK(bufp, gc, H0, M0, H1, M1) do {                               \
        const char* _xb = (bufp);                                              \
        const int _c = (gc) & 1;                                               \
        f16x8 ah[4], am[4];                                                    \
        _Pragma("unroll")                                                      \
        for (int ms = 0; ms < 4; ++ms) {                                       \
            const int so = (((_c << 2) | kq) ^ swz[ms]) << 4;                  \
            ah[ms] = *reinterpret_cast<const f16x8*>(_xb + rbase[ms] + so);    \
            am[ms] = *reinterpret_cast<const f16x8*>(_xb + rbase[ms] + 128 + so);\
        }                                                                      \
        _Pragma("unroll")                                                      \
        for (int ms = 0; ms < 4; ++ms) {                                       \
            acc[ms][0] = __builtin_amdgcn_mfma_f32_16x16x32_f16(ah[ms], H0, acc[ms][0], 0,0,0); \
            acc[ms][1] = __builtin_amdgcn_mfma_f32_16x16x32_f16(ah[ms], H1, acc[ms][1], 0,0,0); \
        }                                                                      \
        _Pragma("unroll")                                                      \
        for (int ms = 0; ms < 4; ++ms) {                                       \
            acc[ms][0] = __builtin_amdgcn_mfma_f32_16x16x32_f16(am[ms], H0, acc[ms][0], 0,0,0); \
            acc[ms][1] = __builtin_amdgcn_mfma_f32_16x16x32_f16(am[ms], H1, acc[ms][1], 0,0,0); \
        }                                                                      \
        _Pragma("unroll")                                                      \
        for (int ms = 0; ms < 4; ++ms) {                                       \
            acc[ms][0] = __builtin_amdgcn_mfma_f32_16x16x32_f16(ah[ms], M0, acc[ms][0], 0,0,0); \
            acc[ms][1] = __builtin_amdgcn_mfma_f32_16x16x32_f16(ah[ms], M1, acc[ms][1], 0,0,0); \
        }                                                                      \
        { const int _g = (gc) + 2;                                             \
          LOADB((_g <= GMAX) ? _g : GMAX, H0, M0, H1, M1); }                   \
    } while (0)

    float4 xa0, xa1, xa2, xa3;          // x reg set A
    float4 xb0, xb1, xb2, xb3;          // x reg set B
    f16x8 pH0, pM0, pH1, pM1;           // B set for even chunks
    f16x8 qH0, qM0, qH1, qM1;           // B set for odd chunks

    // ---- prologue ----
    if (producer) {
        LOADX(0, xa0, xa1, xa2, xa3);
        WSPLIT(buf0, xa0, xa1, xa2, xa3);
        LOADX(1, xb0, xb1, xb2, xb3);
    } else {
        LOADB(0, pH0, pM0, pH1, pM1);
        LOADB(1, qH0, qM0, qH1, qM1);
    }

    // ---- main loop (2 steps per trip; 1 lgkmcnt+barrier per step) ----
    for (int t = 0; t < NKS; t += 2) {
        // even step t: consumers compute buf0; producers write x(t+1)->buf1
        asm volatile("s_waitcnt lgkmcnt(0)" ::: "memory");
        __builtin_amdgcn_s_barrier();
        if (producer) {
            if (t + 2 < NKS) LOADX(t + 2, xa0, xa1, xa2, xa3);
            WSPLIT(buf1, xb0, xb1, xb2, xb3);
        } else {
            CHUNK(buf0, 2 * t,     pH0, pM0, pH1, pM1);
            CHUNK(buf0, 2 * t + 1, qH0, qM0, qH1, qM1);
        }

        // odd step t+1: consumers compute buf1; producers write x(t+2)->buf0
        asm volatile("s_waitcnt lgkmcnt(0)" ::: "memory");
        __builtin_amdgcn_s_barrier();
        if (producer) {
            if (t + 3 < NKS) LOADX(t + 3, xb0, xb1, xb2, xb3);
            if (t + 2 < NKS) WSPLIT(buf0, xa0, xa1, xa2, xa3);
        } else {
            CHUNK(buf1, 2 * t + 2, pH0, pM0, pH1, pM1);
            CHUNK(buf1, 2 * t + 3, qH0, qM0, qH1, qM1);
        }
    }

    #undef LOADX
    #undef WSPLIT
    #undef LOADB
    #undef CHUNK

    // ---- partial logits out (consumers only; deterministic) ----
    if (!producer) {
        const size_t pbase = ((size_t)sk * BB + row0) * 128;
        #pragma unroll
        for (int ms = 0; ms < 4; ++ms) {
            #pragma unroll
            for (int cb = 0; cb < 2; ++cb) {
                #pragma unroll
                for (int j = 0; j < 4; ++j) {
                    const int r = ms * 16 + kq * 4 + j;
                    const int c = (2 * cw + cb) * 16 + l15;
                    partial[pbase + (size_t)r * 128 + c] = acc[ms][cb][j];
                }
            }
        }
    }
}

// ------------------------------- epilogue ---------------------------------
template <int SK>
__global__ __launch_bounds__(512) void gating_epi(
    const float* __restrict__ partial,   // [SK][BB][128]
    const float* __restrict__ noise,     // [B, E]
    float* __restrict__ out)             // gates [B,E] then load [B,E]
{
    const int tid  = threadIdx.x;
    const int wv   = tid >> 6;
    const int lane = tid & 63;
    const int l15  = lane & 15;
    const int kq   = lane >> 4;
    const int grow = blockIdx.x * 32 + wv * 4 + kq;
    const int s    = l15;                // experts 4s..4s+3

    const float* pb = partial + (size_t)grow * 128 + 4 * s;
    float4 c4 = {0.f,0.f,0.f,0.f}, n4 = {0.f,0.f,0.f,0.f};
    #pragma unroll
    for (int k = 0; k < SK; ++k) {
        const float* p = pb + (size_t)k * BB * 128;
        float4 a = *reinterpret_cast<const float4*>(p);
        float4 b = *reinterpret_cast<const float4*>(p + 64);
        c4.x += a.x; c4.y += a.y; c4.z += a.z; c4.w += a.w;
        n4.x += b.x; n4.y += b.y; n4.z += b.z; n4.w += b.w;
    }

    float4 nz = *reinterpret_cast<const float4*>(noise + (size_t)grow * EE + 4 * s);

    float cc[4] = {c4.x, c4.y, c4.z, c4.w};
    float nl[4] = {n4.x, n4.y, n4.z, n4.w};
    float m1 = -3.4e38f, m2 = -3.4e38f;
    int   i1 = -1, i2 = -1;
    float cmax = -3.4e38f;
    #pragma unroll
    for (int j = 0; j < 4; ++j) {
        const int e = 4 * s + j;
        float sp  = fmaxf(nl[j], 0.0f) + log1pf(expf(-fabsf(nl[j])));  // softplus
        float nzj = (j == 0) ? nz.x : (j == 1) ? nz.y : (j == 2) ? nz.z : nz.w;
        float vno = fmaf(nzj * sp, NOISE_EPS, cc[j]);
        if (vno > m1)      { m2 = m1; i2 = i1; m1 = vno; i1 = e; }
        else if (vno > m2) { m2 = vno; i2 = e; }
        cmax = fmaxf(cmax, cc[j]);
    }

    // 16-lane reduce: top-2 with (value, lower-index) tiebreak + clean max
    #pragma unroll
    for (int m = 1; m < 16; m <<= 1) {
        float b1 = __shfl_xor(m1, m, 16);
        int  bi1 = __shfl_xor(i1, m, 16);
        float b2 = __shfl_xor(m2, m, 16);
        int  bi2 = __shfl_xor(i2, m, 16);
        cmax = fmaxf(cmax, __shfl_xor(cmax, m, 16));

        bool bwin = (b1 > m1) || (b1 == m1 && bi1 < i1);
        float t1; int ti1; float t2; int ti2;
        if (bwin) {
            t1 = b1; ti1 = bi1;
            bool aw = (m1 > b2) || (m1 == b2 && i1 < bi2);
            t2 = aw ? m1 : b2; ti2 = aw ? i1 : bi2;
        } else {
            t1 = m1; ti1 = i1;
            bool bw = (b1 > m2) || (b1 == m2 && bi1 < i2);
            t2 = bw ? b1 : m2; ti2 = bw ? bi1 : i2;
        }
        m1 = t1; i1 = ti1; m2 = t2; i2 = ti2;
    }

    float tq = expf(m2 - m1);
    float p1 = 1.0f / (1.0f + tq);
    float p2 = tq * p1;

    float e0 = expf(cc[0] - cmax);
    float e1 = expf(cc[1] - cmax);
    float e2 = expf(cc[2] - cmax);
    float e3 = expf(cc[3] - cmax);
    float sum = e0 + e1 + e2 + e3;
    #pragma unroll
    for (int m = 1; m < 16; m <<= 1) sum += __shfl_xor(sum, m, 16);
    float inv = 1.0f / sum;

    const int eb = 4 * s;
    float4 gt;
    gt.x = (eb     == i1) ? p1 : (eb     == i2) ? p2 : 0.0f;
    gt.y = (eb + 1 == i1) ? p1 : (eb + 1 == i2) ? p2 : 0.0f;
    gt.z = (eb + 2 == i1) ? p1 : (eb + 2 == i2) ? p2 : 0.0f;
    gt.w = (eb + 3 == i1) ? p1 : (eb + 3 == i2) ? p2 : 0.0f;
    float4 ld = {e0 * inv, e1 * inv, e2 * inv, e3 * inv};

    *reinterpret_cast<float4*>(out + (size_t)grow * EE + eb) = gt;
    *reinterpret_cast<float4*>(out + (size_t)BB * EE + (size_t)grow * EE + eb) = ld;
}

extern "C" void kernel_launch(void* const* d_in, const int* in_sizes, int n_in,
                              void* d_out, int out_size, void* d_ws, size_t ws_size,
                              hipStream_t stream) {
    const float* x     = (const float*)d_in[0];
    const float* gw    = (const float*)d_in[1];
    const float* ngw   = (const float*)d_in[2];
    const float* noise = (const float*)d_in[3];
    float* out = (float*)d_out;

    char*  wpk     = (char*)d_ws;                                // 2 MB packed w
    float* partial = (float*)(wpk + (size_t)2 * 1024 * 1024);    // SK * 4 MB

    const size_t MB = 1024 * 1024;

    hipLaunchKernelGGL(wsplit_pack, dim3(256), dim3(256), 0, stream, gw, ngw, wpk);

    if (ws_size >= 18 * MB) {
        hipLaunchKernelGGL(gating_main<4>, dim3((BB / BM) * 4), dim3(512), 0, stream,
                           x, wpk, partial);
        hipLaunchKernelGGL(gating_epi<4>, dim3(BB / 32), dim3(512), 0, stream,
                           partial, noise, out);
    } else if (ws_size >= 10 * MB) {
        hipLaunchKernelGGL(gating_main<2>, dim3((BB / BM) * 2), dim3(512), 0, stream,
                           x, wpk, partial);
        hipLaunchKernelGGL(gating_epi<2>, dim3(BB / 32), dim3(512), 0, stream,
                           partial, noise, out);
    } else {
        hipLaunchKernelGGL(gating_main<1>, dim3(BB / BM), dim3(512), 0, stream,
                           x, wpk, partial);
        hipLaunchKernelGGL(gating_epi<1>, dim3(BB / 32), dim3(512), 0, stream,
                           partial, noise, out);
    }
}